// Round 3
// baseline (446.837 us; speedup 1.0000x reference)
//
#include <hip/hip_runtime.h>

typedef unsigned short u16;
typedef unsigned int u32;
typedef float f32x4v __attribute__((ext_vector_type(4)));
typedef __bf16 bf16x8 __attribute__((ext_vector_type(8)));

#define GAS __attribute__((address_space(1)))
#define LAS __attribute__((address_space(3)))

__device__ __forceinline__ u16 f2bf(float f) {
  u32 u = __builtin_bit_cast(u32, f);
  u32 r = (u + 0x7FFFu + ((u >> 16) & 1u)) >> 16;  // RNE
  return (u16)r;
}
__device__ __forceinline__ float bf2f(u16 h) {
  return __builtin_bit_cast(float, (u32)h << 16);
}
__device__ __forceinline__ void gld_lds16(const void* g, void* l) {
  __builtin_amdgcn_global_load_lds((const GAS void*)g, (LAS void*)l, 16, 0, 0);
}

// ---------------------------------------------------------------------------
// MFMA GEMM via global_load_lds, 128x128 tile, dbuf, ONE barrier per K-step.
//   C = A(MxK) * B(NxK)^T ; z = zb*S + s ; k-range [s*Kc, ...)
// OUT 0: fp32 partial at C + z*strC.  OUT 1: bf16 final at C + zb*strC, *scale.
// A,B bf16 row-major [*, fullK]. M/N tails handled by clamp+discard.
// ---------------------------------------------------------------------------
template <int BK, int OUT>
__global__ __launch_bounds__(256) void gemm_glds(
    const u16* __restrict__ A, const u16* __restrict__ B, void* __restrict__ C,
    int M, int N, int Kc, int fullK, int S,
    long strA, long strB, long strC, float scale)
{
  constexpr int CPR = BK / 8;    // 16B chunks per LDS row
  constexpr int ISS = BK / 16;   // global_load_lds issues per operand
  __shared__ u16 sA[2][128 * BK];
  __shared__ u16 sB[2][128 * BK];
  const int t = threadIdx.x, lane = t & 63, wave = t >> 6;
  const int z = blockIdx.z, zb = z / S, s = z - zb * S;
  const int m0 = blockIdx.x * 128, n0 = blockIdx.y * 128;
  const int kbeg = s * Kc;

  const u16* Aptr[ISS]; const u16* Bptr[ISS]; int lofs[ISS];
  #pragma unroll
  for (int i = 0; i < ISS; ++i) {
    const int tp = i * 256 + t;
    const int r = tp / CPR, c16 = tp % CPR;
    int ra = m0 + r; if (ra >= M) ra = M - 1;
    int rb = n0 + r; if (rb >= N) rb = N - 1;
    Aptr[i] = A + (long)zb * strA + (long)ra * fullK + kbeg + c16 * 8;
    Bptr[i] = B + (long)zb * strB + (long)rb * fullK + kbeg + c16 * 8;
    lofs[i] = (i * 256 + (wave << 6)) * 8;
  }
  auto stage = [&](int buf, int k0) {
    #pragma unroll
    for (int i = 0; i < ISS; ++i) {
      gld_lds16(Aptr[i] + k0, &sA[buf][lofs[i]]);
      gld_lds16(Bptr[i] + k0, &sB[buf][lofs[i]]);
    }
  };

  const int wr = (wave >> 1) * 64, wc = (wave & 1) * 64;
  const int lr = lane & 15, lg = (lane >> 4) * 8;
  f32x4v acc[4][4] = {};
  const int niter = Kc / BK;

  stage(0, 0);
  __syncthreads();
  for (int it = 0; it < niter; ++it) {
    const int cur = it & 1;
    if (it + 1 < niter) stage(cur ^ 1, (it + 1) * BK);
    #pragma unroll
    for (int kk = 0; kk < BK; kk += 32) {
      const int lk = kk + lg;
      bf16x8 af[4], bv[4];
      #pragma unroll
      for (int i = 0; i < 4; ++i) af[i] = *(const bf16x8*)&sA[cur][(wr + i*16 + lr) * BK + lk];
      #pragma unroll
      for (int j = 0; j < 4; ++j) bv[j] = *(const bf16x8*)&sB[cur][(wc + j*16 + lr) * BK + lk];
      #pragma unroll
      for (int i = 0; i < 4; ++i)
        #pragma unroll
        for (int j = 0; j < 4; ++j)
          acc[i][j] = __builtin_amdgcn_mfma_f32_16x16x32_bf16(af[i], bv[j], acc[i][j], 0, 0, 0);
    }
    __syncthreads();
  }

  // D: lane l reg r -> row=(l>>4)*4+r, col=l&15
  const int lq = (lane >> 4) * 4;
  if constexpr (OUT == 0) {
    float* Cp = (float*)C + (long)z * strC;
    #pragma unroll
    for (int i = 0; i < 4; ++i)
      #pragma unroll
      for (int r = 0; r < 4; ++r) {
        const int row = m0 + wr + i*16 + lq + r;
        if (row >= M) continue;
        #pragma unroll
        for (int j = 0; j < 4; ++j) {
          const int col = n0 + wc + j*16 + lr;
          if (col < N) Cp[(long)row * N + col] = acc[i][j][r];
        }
      }
  } else {
    u16* Cp = (u16*)C + (long)zb * strC;
    #pragma unroll
    for (int i = 0; i < 4; ++i)
      #pragma unroll
      for (int r = 0; r < 4; ++r) {
        const int row = m0 + wr + i*16 + lq + r;
        if (row >= M) continue;
        #pragma unroll
        for (int j = 0; j < 4; ++j) {
          const int col = n0 + wc + j*16 + lr;
          if (col < N) Cp[(long)row * N + col] = f2bf(acc[i][j][r] * scale);
        }
      }
  }
}

// ---------------------------------------------------------------------------
// Implicit-GEMM 3x3 conv over zero-PADDED channel-last images [nImg][900][Cin]
// (30x30 frame, interior = 28x28). Wt: [M][9*Cin] tap-major bf16.
// Merged-N pixels (Ntot = nImg*784). z = K-chunk; partial fp32 at Cp+z*M*Ntot.
// ---------------------------------------------------------------------------
__global__ __launch_bounds__(256) void conv_glds(
    const u16* __restrict__ Wt, const u16* __restrict__ imgP,
    float* __restrict__ Cp, int M, int Cin, int Ntot, int Kc)
{
  __shared__ u16 sA[2][128 * 32];
  __shared__ u16 sB[2][128 * 32];
  const int t = threadIdx.x, lane = t & 63, wave = t >> 6;
  const int z = blockIdx.z;
  const int m0 = blockIdx.x * 128, n0 = blockIdx.y * 128;
  const int kbeg = z * Kc;

  const u16* Aptr[2]; const u16* Bptr[2]; int lofs[2];
  #pragma unroll
  for (int i = 0; i < 2; ++i) {
    const int tp = i * 256 + t;
    const int r = tp >> 2, c16 = tp & 3;
    int ra = m0 + r; if (ra >= M) ra = M - 1;
    int pn = n0 + r; if (pn >= Ntot) pn = 0;
    const int img = pn / 784, p = pn - img * 784;
    const int py = p / 28, px = p - py * 28;
    Aptr[i] = Wt + (long)ra * (9 * Cin) + c16 * 8;
    Bptr[i] = imgP + ((long)img * 900 + (py + 1) * 30 + (px + 1)) * Cin + c16 * 8;
    lofs[i] = (i * 256 + (wave << 6)) * 8;
  }
  auto stage = [&](int buf, int kg) {
    const int tap = kg / Cin, kc = kg - tap * Cin;
    const int off = ((tap / 3 - 1) * 30 + (tap % 3 - 1)) * Cin + kc;
    #pragma unroll
    for (int i = 0; i < 2; ++i) {
      gld_lds16(Aptr[i] + kg, &sA[buf][lofs[i]]);
      gld_lds16(Bptr[i] + off, &sB[buf][lofs[i]]);
    }
  };

  const int wr = (wave >> 1) * 64, wc = (wave & 1) * 64;
  const int lr = lane & 15, lk = (lane >> 4) * 8;
  f32x4v acc[4][4] = {};
  const int niter = Kc >> 5;

  stage(0, kbeg);
  __syncthreads();
  for (int it = 0; it < niter; ++it) {
    const int cur = it & 1;
    if (it + 1 < niter) stage(cur ^ 1, kbeg + (it + 1) * 32);
    bf16x8 af[4], bv[4];
    #pragma unroll
    for (int i = 0; i < 4; ++i) af[i] = *(const bf16x8*)&sA[cur][(wr + i*16 + lr) * 32 + lk];
    #pragma unroll
    for (int j = 0; j < 4; ++j) bv[j] = *(const bf16x8*)&sB[cur][(wc + j*16 + lr) * 32 + lk];
    #pragma unroll
    for (int i = 0; i < 4; ++i)
      #pragma unroll
      for (int j = 0; j < 4; ++j)
        acc[i][j] = __builtin_amdgcn_mfma_f32_16x16x32_bf16(af[i], bv[j], acc[i][j], 0, 0, 0);
    __syncthreads();
  }

  float* Co = Cp + (long)z * M * Ntot;
  const int lq = (lane >> 4) * 4;
  #pragma unroll
  for (int i = 0; i < 4; ++i)
    #pragma unroll
    for (int r = 0; r < 4; ++r) {
      const int row = m0 + wr + i*16 + lq + r;
      if (row >= M) continue;
      #pragma unroll
      for (int j = 0; j < 4; ++j) {
        const int col = n0 + wc + j*16 + lr;
        if (col < Ntot) Co[(long)row * Ntot + col] = acc[i][j][r];
      }
    }
}

// ---------------------------------------------------------------------------
// Plain transpose fp32 -> bf16: out[z*strOutZ + c*ldOut + colOff + r]
// ---------------------------------------------------------------------------
__global__ __launch_bounds__(256) void transpose_bf(
    const float* __restrict__ in, u16* __restrict__ out,
    int R, int C, long strOutZ, int ldOut, int colOff)
{
  __shared__ float tile[32][33];
  in  += (long)blockIdx.z * R * C;
  out += (long)blockIdx.z * strOutZ;
  const int c0 = blockIdx.x * 32, r0 = blockIdx.y * 32;
  const int tx = threadIdx.x & 31, ty = threadIdx.x >> 5;
  for (int i = ty; i < 32; i += 8) {
    const int r = r0 + i, c = c0 + tx;
    tile[i][tx] = (r < R && c < C) ? in[(long)r * C + c] : 0.0f;
  }
  __syncthreads();
  for (int i = ty; i < 32; i += 8) {
    const int r = r0 + tx, c = c0 + i;
    if (c < C && r < R)
      out[(long)c * ldOut + colOff + r] = f2bf(tile[tx][i]);
  }
}

__global__ __launch_bounds__(256) void convert_bf(
    const float* __restrict__ in, u16* __restrict__ out, long n8)
{
  const long i = (long)blockIdx.x * 256 + threadIdx.x;
  if (i >= n8) return;
  const float4* p = (const float4*)in + i * 2;
  const float4 a = p[0], b = p[1];
  u16 o[8] = {f2bf(a.x), f2bf(a.y), f2bf(a.z), f2bf(a.w),
              f2bf(b.x), f2bf(b.y), f2bf(b.z), f2bf(b.w)};
  ((uint4*)out)[i] = *(uint4*)o;
}

// weight reorder: dst[m][tap][c] = src[m][c][tap]  (bf16)
__global__ __launch_bounds__(256) void permute_w(
    const float* __restrict__ src, u16* __restrict__ dst, int M, int Cin)
{
  const long total = (long)M * 9 * Cin;
  const long idx = (long)blockIdx.x * 256 + threadIdx.x;
  if (idx >= total) return;
  const int c = (int)(idx % Cin);
  const int tap = (int)((idx / Cin) % 9);
  const int m = (int)(idx / ((long)9 * Cin));
  dst[idx] = f2bf(src[((long)m * Cin + c) * 9 + tap]);
}

__global__ __launch_bounds__(256) void zfill(u32* __restrict__ p, long n) {
  const long stride = (long)gridDim.x * 256;
  for (long i = (long)blockIdx.x * 256 + threadIdx.x; i < n; i += stride) p[i] = 0;
}

// ---------------------------------------------------------------------------
// Transposing reduces (32x32 tiles): parts fp32 -> bf16 channel-last dests
// ---------------------------------------------------------------------------
// conv1: parts[S][512][1568] -> out1P[b][900pad][512] (+b1)
__global__ __launch_bounds__(256) void reduceT_c1(
    const float* __restrict__ parts, u16* __restrict__ dst,
    const float* __restrict__ bias, int S)
{
  __shared__ float tile[32][33];
  const int b = blockIdx.z, c0 = blockIdx.x * 32, p0 = blockIdx.y * 32;
  const int tx = threadIdx.x & 31, ty = threadIdx.x >> 5;
  for (int i = ty; i < 32; i += 8) {
    const int pc = min(p0 + tx, 783);
    const long base = (long)(c0 + i) * 1568 + b * 784 + pc;
    float s = 0;
    for (int k = 0; k < S; ++k) s += parts[(long)k * 512 * 1568 + base];
    tile[i][tx] = s;
  }
  __syncthreads();
  for (int i = ty; i < 32; i += 8) {
    const int p = p0 + i, c = c0 + tx;
    if (p < 784) {
      const int qpad = (p / 28 + 1) * 30 + (p % 28 + 1);
      dst[((long)b * 900 + qpad) * 512 + c] = f2bf(tile[tx][i] + bias[c]);
    }
  }
}

// conv2: parts[S][64][1568] -> qkT[b][784][64] (+b2)
__global__ __launch_bounds__(256) void reduceT_qk(
    const float* __restrict__ parts, u16* __restrict__ dst,
    const float* __restrict__ bias, int S)
{
  __shared__ float tile[32][33];
  const int b = blockIdx.z, c0 = blockIdx.x * 32, p0 = blockIdx.y * 32;
  const int tx = threadIdx.x & 31, ty = threadIdx.x >> 5;
  for (int i = ty; i < 32; i += 8) {
    const int pc = min(p0 + tx, 783);
    const long base = (long)(c0 + i) * 1568 + b * 784 + pc;
    float s = 0;
    for (int k = 0; k < S; ++k) s += parts[(long)k * 64 * 1568 + base];
    tile[i][tx] = s;
  }
  __syncthreads();
  for (int i = ty; i < 32; i += 8) {
    const int p = p0 + i, c = c0 + tx;
    if (p < 784)
      dst[((long)b * 784 + p) * 64 + c] = f2bf(tile[tx][i] + bias[c]);
  }
}

// readout: parts[(b*S+s)][1536][784] -> concatP[b*3+n][900pad][ch 0..511]
__global__ __launch_bounds__(256) void reduceT_ro(
    const float* __restrict__ parts, u16* __restrict__ dst, int S)
{
  __shared__ float tile[32][33];
  const int zimg = blockIdx.z, b = zimg / 3, n = zimg % 3;
  const int c0 = blockIdx.x * 32, p0 = blockIdx.y * 32;
  const int tx = threadIdx.x & 31, ty = threadIdx.x >> 5;
  for (int i = ty; i < 32; i += 8) {
    const int pc = min(p0 + tx, 783);
    float s = 0;
    for (int k = 0; k < S; ++k)
      s += parts[((long)(b * S + k) * 1536 + n * 512 + c0 + i) * 784 + pc];
    tile[i][tx] = s;
  }
  __syncthreads();
  for (int i = ty; i < 32; i += 8) {
    const int p = p0 + i, c = c0 + tx;
    if (p < 784) {
      const int qpad = (p / 28 + 1) * 30 + (p % 28 + 1);
      dst[((long)zimg * 900 + qpad) * 768 + c] = f2bf(tile[tx][i]);
    }
  }
}

// h: hin[img][256][784] -> concatP[img][900pad][ch 512..767]
__global__ __launch_bounds__(256) void transT_h(
    const float* __restrict__ h, u16* __restrict__ dst)
{
  __shared__ float tile[32][33];
  const int zimg = blockIdx.z, c0 = blockIdx.x * 32, p0 = blockIdx.y * 32;
  const int tx = threadIdx.x & 31, ty = threadIdx.x >> 5;
  for (int i = ty; i < 32; i += 8) {
    const int pc = min(p0 + tx, 783);
    tile[i][tx] = h[((long)zimg * 256 + c0 + i) * 784 + pc];
  }
  __syncthreads();
  for (int i = ty; i < 32; i += 8) {
    const int p = p0 + i, c = c0 + tx;
    if (p < 784) {
      const int qpad = (p / 28 + 1) * 30 + (p % 28 + 1);
      dst[((long)zimg * 900 + qpad) * 768 + 512 + c] = f2bf(tile[tx][i]);
    }
  }
}

// ---------------------------------------------------------------------------
// In-place softmax over rows of 12544 bf16 (one block per row)
// ---------------------------------------------------------------------------
__global__ __launch_bounds__(256) void softmax_inplace(u16* __restrict__ buf)
{
  u16* ptr = buf + (long)blockIdx.x * 12544;
  uint4* p4 = (uint4*)ptr;
  const int t = threadIdx.x;
  __shared__ float red[4];
  float mx = -3.0e38f;
  for (int v = t; v < 1568; v += 256) {
    uint4 u = p4[v];
    const u32 w[4] = {u.x, u.y, u.z, u.w};
    #pragma unroll
    for (int q = 0; q < 4; ++q) {
      mx = fmaxf(mx, bf2f((u16)(w[q] & 0xFFFFu)));
      mx = fmaxf(mx, bf2f((u16)(w[q] >> 16)));
    }
  }
  #pragma unroll
  for (int o = 32; o > 0; o >>= 1) mx = fmaxf(mx, __shfl_xor(mx, o));
  if ((t & 63) == 0) red[t >> 6] = mx;
  __syncthreads();
  mx = fmaxf(fmaxf(red[0], red[1]), fmaxf(red[2], red[3]));

  float s = 0.0f;
  for (int v = t; v < 1568; v += 256) {
    uint4 u = p4[v];
    const u32 w[4] = {u.x, u.y, u.z, u.w};
    #pragma unroll
    for (int q = 0; q < 4; ++q) {
      s += __expf(bf2f((u16)(w[q] & 0xFFFFu)) - mx);
      s += __expf(bf2f((u16)(w[q] >> 16)) - mx);
    }
  }
  #pragma unroll
  for (int o = 32; o > 0; o >>= 1) s += __shfl_xor(s, o);
  __syncthreads();
  if ((t & 63) == 0) red[t >> 6] = s;
  __syncthreads();
  const float inv = 1.0f / (red[0] + red[1] + red[2] + red[3]);

  for (int v = t; v < 1568; v += 256) {
    uint4 u = p4[v];
    u32 w[4] = {u.x, u.y, u.z, u.w};
    #pragma unroll
    for (int q = 0; q < 4; ++q) {
      const float a = __expf(bf2f((u16)(w[q] & 0xFFFFu)) - mx) * inv;
      const float b = __expf(bf2f((u16)(w[q] >> 16)) - mx) * inv;
      w[q] = (u32)f2bf(a) | ((u32)f2bf(b) << 16);
    }
    p4[v] = make_uint4(w[0], w[1], w[2], w[3]);
  }
}

// ---------------------------------------------------------------------------
// Fused transform-reduce + gating. parts: [S][768][4704] fp32 merged-N.
// ---------------------------------------------------------------------------
__global__ __launch_bounds__(256) void treduce_gate(
    const float* __restrict__ parts, const float* __restrict__ bt,
    const float* __restrict__ h, float* __restrict__ out, int S)
{
  const long i = (long)blockIdx.x * 256 + threadIdx.x;
  if (i >= 6L * 256 * 196) return;
  const int p4 = (int)(i % 196);
  const int rest = (int)(i / 196);
  const int cs = rest % 256, im = rest / 256;
  const long slice4 = (768L * 4704) >> 2;
  const long colBase = ((long)im * 784) >> 2;
  f32x4v F = {0,0,0,0}, U = {0,0,0,0}, NV = {0,0,0,0};
  for (int s = 0; s < S; ++s) {
    const f32x4v* P = (const f32x4v*)parts + (long)s * slice4;
    F  += P[(((long)cs        * 4704) >> 2) + colBase + p4];
    U  += P[(((long)(256 + cs) * 4704) >> 2) + colBase + p4];
    NV += P[(((long)(512 + cs) * 4704) >> 2) + colBase + p4];
  }
  const float bF = bt[cs], bU = bt[256 + cs], bN = bt[512 + cs];
  const f32x4v hv = ((const f32x4v*)h)[((long)(im * 256 + cs) * 784 >> 2) + p4];
  f32x4v o;
  #pragma unroll
  for (int q = 0; q < 4; ++q) {
    const float f = F[q] + bF, u = U[q] + bU, nv = NV[q] + bN;
    const float sf = 1.0f / (1.0f + __expf(-f));
    const float su = 1.0f / (1.0f + __expf(-u));
    const float e2 = __expf(2.0f * nv);
    const float tv = (e2 - 1.0f) / (e2 + 1.0f);
    o[q] = sf * hv[q] * (1.0f - su) + su * tv;
  }
  ((f32x4v*)out)[((long)(im * 256 + cs) * 784 >> 2) + p4] = o;
}

__global__ __launch_bounds__(256) void fill_sentinel(float* p, long n) {
  const long i = (long)blockIdx.x * 256 + threadIdx.x;
  if (i < n) p[i] = 12345.0f;
}

// ---------------------------------------------------------------------------
extern "C" void kernel_launch(void* const* d_in, const int* in_sizes, int n_in,
                              void* d_out, int out_size, void* d_ws, size_t ws_size,
                              hipStream_t stream) {
  const float* f16 = (const float*)d_in[0];
  const float* mk  = (const float*)d_in[1];
  const float* mv  = (const float*)d_in[2];
  const float* hin = (const float*)d_in[3];
  const float* w1  = (const float*)d_in[4];
  const float* b1  = (const float*)d_in[5];
  const float* w2  = (const float*)d_in[6];
  const float* b2  = (const float*)d_in[7];
  const float* wt  = (const float*)d_in[8];
  const float* bt  = (const float*)d_in[9];
  float* out = (float*)d_out;

  // ---- byte sizes ----
  const size_t B_f16T   = 2UL*784*1024*2;
  const size_t B_w1b    = 512UL*1024*2;
  const size_t B_w2R    = 64UL*4608*2;
  const size_t B_out1P  = 2UL*900*512*2;
  const size_t B_qkT    = 2UL*784*64*2;
  const size_t B_concat = 6UL*900*768*2;
  const size_t B_wtR    = 768UL*6912*2;
  const size_t B_mkT    = 2UL*12544*64*2;
  const size_t B_logaff = 2UL*784*12544*2;
  const size_t B_mvb    = 38535168UL*2;
  auto al = [](size_t x) { return (x + 255) & ~(size_t)255; };

  const size_t phase1 = al(B_f16T) + al(B_w1b) + al(B_w2R) + al(B_out1P) + al(B_qkT);
  const size_t regionA = phase1 > al(B_concat) ? phase1 : al(B_concat);

  auto poolFor = [&](int S_ro, int S_tr) -> size_t {
    size_t p1 = 8UL*512*1568*4, p2 = 18UL*64*1568*4;
    size_t pr = (size_t)(2*S_ro)*1536*784*4, pt = (size_t)S_tr*768*4704*4;
    size_t m = p1; if (p2 > m) m = p2; if (pr > m) m = pr; if (pt > m) m = pt;
    return m;
  };
  const size_t fixed = regionA + al(B_wtR) + al(B_mkT) + al(B_logaff) + al(B_mvb);

  int S_ro = 7, S_tr = 4;
  if (fixed + poolFor(7, 4) > ws_size) { S_ro = 4; S_tr = 4; }
  if (S_ro == 4 && fixed + poolFor(4, 4) > ws_size) { S_ro = 4; S_tr = 3; }
  if (fixed + poolFor(S_ro, S_tr) > ws_size) {
    fill_sentinel<<<4704, 256, 0, stream>>>(out, (long)out_size);
    return;
  }

  // ---- layout ----
  char* base = (char*)d_ws;
  size_t off = 0;
  auto alloc = [&](size_t bytes) -> char* { char* p = base + off; off += al(bytes); return p; };
  char* rA = alloc(regionA);
  u16* f16T   = (u16*)rA;
  u16* w1b    = (u16*)(rA + al(B_f16T));
  u16* w2R    = (u16*)(rA + al(B_f16T) + al(B_w1b));
  u16* out1P  = (u16*)(rA + al(B_f16T) + al(B_w1b) + al(B_w2R));
  u16* qkT    = (u16*)(rA + al(B_f16T) + al(B_w1b) + al(B_w2R) + al(B_out1P));
  u16* concatP = (u16*)rA;  // overlays phase-1 buffers (all dead before use)
  u16*   wtR    = (u16*)alloc(B_wtR);
  u16*   mkT    = (u16*)alloc(B_mkT);
  u16*   logaff = (u16*)alloc(B_logaff);
  u16*   mvb    = (u16*)alloc(B_mvb);
  float* parts  = (float*)alloc(poolFor(S_ro, S_tr));

  // ---- 0) zero padded conv1 image (borders must be 0) ----
  zfill<<<512, 256, 0, stream>>>((u32*)out1P, (long)(B_out1P / 4));

  // ---- operand prep ----
  convert_bf<<<256, 256, 0, stream>>>(w1, w1b, 65536);
  permute_w<<<1152, 256, 0, stream>>>(w2, w2R, 64, 512);
  permute_w<<<20736, 256, 0, stream>>>(wt, wtR, 768, 768);
  transpose_bf<<<dim3(25, 32, 2), 256, 0, stream>>>(f16, f16T, 1024, 784, 784L*1024, 1024, 0);
  transpose_bf<<<dim3(392, 2, 2), 256, 0, stream>>>(mk, mkT, 64, 12544, 12544L*64, 64, 0);
  convert_bf<<<18816, 256, 0, stream>>>(mv, mvb, 4816896);

  // ---- conv1 (1x1): M=512, N=1568 (merged), K=1024, S=8 ----
  gemm_glds<32, 0><<<dim3(4, 13, 8), 256, 0, stream>>>(
      w1b, f16T, parts, 512, 1568, 128, 1024, 8, 0, 0, 512L*1568, 1.0f);
  reduceT_c1<<<dim3(16, 25, 2), 256, 0, stream>>>(parts, out1P, b1, 8);

  // ---- conv2 (3x3 implicit): M=64, Cin=512, Ntot=1568, S=18 ----
  conv_glds<<<dim3(1, 13, 18), 256, 0, stream>>>(w2R, out1P, parts, 64, 512, 1568, 256);
  reduceT_qk<<<dim3(2, 25, 2), 256, 0, stream>>>(parts, qkT, b2, 18);

  // ---- logits: M=784, N=12544, K=64, scale 1/8 -> bf16 ----
  gemm_glds<64, 1><<<dim3(7, 98, 2), 256, 0, stream>>>(
      qkT, mkT, logaff, 784, 12544, 64, 64, 1,
      784L*64, 12544L*64, 784L*12544, 0.125f);

  // ---- softmax over memory axis ----
  softmax_inplace<<<1568, 256, 0, stream>>>(logaff);

  // ---- zero concat image (phase-1 buffers dead now) ----
  zfill<<<2048, 256, 0, stream>>>((u32*)concatP, (long)(B_concat / 4));

  // ---- readout: per-batch M=1536, N=784, K=12544, split S_ro ----
  gemm_glds<32, 0><<<dim3(12, 7, 2 * S_ro), 256, 0, stream>>>(
      mvb, logaff, parts, 1536, 784, 12544 / S_ro, 12544, S_ro,
      1536L*12544, 784L*12544, 1536L*784, 1.0f);
  reduceT_ro<<<dim3(16, 25, 6), 256, 0, stream>>>(parts, concatP, S_ro);
  transT_h<<<dim3(8, 25, 6), 256, 0, stream>>>(hin, concatP);

  // ---- transform conv (3x3 implicit): M=768, Cin=768, Ntot=4704, S_tr ----
  conv_glds<<<dim3(6, 37, S_tr), 256, 0, stream>>>(
      wtR, concatP, parts, 768, 768, 4704, 6912 / S_tr);

  // ---- fused reduce + gating -> d_out ----
  treduce_gate<<<1176, 256, 0, stream>>>(parts, bt, hin, out, S_tr);
}